// Round 6
// baseline (614.831 us; speedup 1.0000x reference)
//
#include <hip/hip_runtime.h>
#include <hip/hip_bf16.h>
#include <cstdint>

typedef __bf16 bf16x8 __attribute__((ext_vector_type(8)));
typedef __bf16 bf16x4 __attribute__((ext_vector_type(4)));
typedef float  f32x4  __attribute__((ext_vector_type(4)));
typedef float  f32x16 __attribute__((ext_vector_type(16)));
typedef unsigned short u16x16 __attribute__((ext_vector_type(16)));

#define ND 128
#define HID 128

__device__ __forceinline__ f32x16 mfma32(bf16x8 a, bf16x8 b, f32x16 c) {
  return __builtin_amdgcn_mfma_f32_32x32x16_bf16(a, b, c, 0, 0, 0);
}
__device__ __forceinline__ float fast_sigmoid(float x) {
  return __fdividef(1.f, 1.f + __expf(-x));
}
__device__ __forceinline__ float fast_silu(float x) {
  return __fdividef(x, 1.f + __expf(-x));
}
__device__ __forceinline__ float fast_tanh(float x) {
  float cx = fminf(fmaxf(x, -15.f), 15.f);
  float e = __expf(2.f * cx);
  return __fdividef(e - 1.f, e + 1.f);
}
__device__ __forceinline__ f32x4 mfma_bf16(bf16x8 a, bf16x8 b, f32x4 c) {
  return __builtin_amdgcn_mfma_f32_16x16x32_bf16(a, b, c, 0, 0, 0);
}

// ---- fused f32 -> bf16 conversion over 5 segments ----
__global__ void cvt_all(const float* __restrict__ s0, __bf16* __restrict__ d0, int c1,
                        const float* __restrict__ s1, __bf16* __restrict__ d1, int c2,
                        const float* __restrict__ s2, __bf16* __restrict__ d2, int c3,
                        const float* __restrict__ s3, __bf16* __restrict__ d3, int c4,
                        const float* __restrict__ s4, __bf16* __restrict__ d4, int c5) {
  int i = blockIdx.x * blockDim.x + threadIdx.x;
  const float* s; __bf16* d; int j;
  if (i < c1)      { s = s0; d = d0; j = i; }
  else if (i < c2) { s = s1; d = d1; j = i - c1; }
  else if (i < c3) { s = s2; d = d2; j = i - c2; }
  else if (i < c4) { s = s3; d = d3; j = i - c3; }
  else if (i < c5) { s = s4; d = d4; j = i - c4; }
  else return;
  const float4* sp = reinterpret_cast<const float4*>(s) + (size_t)j * 2;
  float4 a = sp[0], b = sp[1];
  bf16x8 v;
  v[0] = (__bf16)a.x; v[1] = (__bf16)a.y; v[2] = (__bf16)a.z; v[3] = (__bf16)a.w;
  v[4] = (__bf16)b.x; v[5] = (__bf16)b.y; v[6] = (__bf16)b.z; v[7] = (__bf16)b.w;
  reinterpret_cast<bf16x8*>(d)[j] = v;
}

// ================= sort machinery =================
__global__ void k_hist(const int* __restrict__ dst, int* __restrict__ counts, int E) {
  int e = blockIdx.x * 256 + threadIdx.x;
  if (e < E) atomicAdd(&counts[dst[e]], 1);
}

__global__ void k_blocksum(const int* __restrict__ counts, int* __restrict__ bsum) {
  __shared__ int sd[256];
  int t = threadIdx.x;
  sd[t] = counts[blockIdx.x * 256 + t];
  __syncthreads();
  for (int d = 128; d > 0; d >>= 1) { if (t < d) sd[t] += sd[t + d]; __syncthreads(); }
  if (!t) bsum[blockIdx.x] = sd[0];
}

__global__ void k_scan_bsum(int* __restrict__ bsum, int nb) {
  __shared__ int sd[256];
  int t = threadIdx.x;
  int v = (t < nb) ? bsum[t] : 0;
  sd[t] = v;
  __syncthreads();
  for (int d = 1; d < 256; d <<= 1) {
    int u = (t >= d) ? sd[t - d] : 0;
    __syncthreads();
    sd[t] += u;
    __syncthreads();
  }
  if (t < nb) bsum[t] = sd[t] - v;
}

__global__ void k_scan_write(const int* __restrict__ counts, const int* __restrict__ bsum,
                             int* __restrict__ cursor) {
  __shared__ int sd[256];
  int t = threadIdx.x, b = blockIdx.x;
  int i = b * 256 + t;
  int c = counts[i];
  sd[t] = c;
  __syncthreads();
  for (int d = 1; d < 256; d <<= 1) {
    int u = (t >= d) ? sd[t - d] : 0;
    __syncthreads();
    sd[t] += u;
    __syncthreads();
  }
  cursor[i] = bsum[b] + sd[t] - c;   // exclusive prefix
}

__global__ void k_perm(const int* __restrict__ dst, int* __restrict__ cursor,
                       int* __restrict__ eperm, int* __restrict__ dsorted, int E) {
  int e = blockIdx.x * 256 + threadIdx.x;
  if (e < E) {
    int d = dst[e];
    int p = atomicAdd(&cursor[d], 1);
    eperm[p] = e;
    dsorted[p] = d;
  }
}

// ================= fused edge MLP + aggregate (32x32 MFMA) =================
// 8 waves = 4 j-strips(32) x 2 slot-halves(32). A tile [64][320B] chunks
// 0..15 = x (^ (s&15)), 16..19 = ea (^ (s&3)). H1 [64][256B] ^ (s&15).
// M (layer-2 out) overlays A as [64][256B] ^ (s&15). Flush: waves 0-3, one
// 16-slot group each, b32 column-pair reads, readlane-uniform segmented scan.
#define TILE_E 64

__global__ __launch_bounds__(512, 4) void edge_mlp3(
    const __bf16* __restrict__ xb,
    const int*    __restrict__ srcp,     // [E]
    const float*  __restrict__ ea,       // [E,32]
    const __bf16* __restrict__ W1b,      // [128,160]
    const float*  __restrict__ b1,
    const __bf16* __restrict__ W2b,      // [128,128]
    const float*  __restrict__ b2,
    const int*    __restrict__ eperm,    // [E] slot -> edge
    const int*    __restrict__ dsorted,  // [E] slot -> dst node
    float* __restrict__ agg,             // [N,128] f32, zeroed
    int ntiles)
{
  __shared__ __bf16 Als[TILE_E * 160];   // 20480 B; first 16 KB reused as M
  __shared__ __bf16 H1[TILE_E * 128];    // 16384 B
  __shared__ int dstls[TILE_E];
  char* AB = (char*)Als;
  char* HB = (char*)H1;

  const int tid = threadIdx.x;
  const int w   = tid >> 6;
  const int l   = tid & 63;
  const int hi  = l >> 5;            // k-half within fragment
  const int sl  = l & 31;
  const int jb  = (w & 3) * 32;      // j-strip base
  const int sh  = (w >> 2) * 32;     // slot-half base
  const int s   = sh + sl;           // this lane's B-operand slot
  const int sw  = s & 15;

  // weight A-fragments: row j = jb + sl, k = kt*16 + hi*8 (16B contiguous)
  bf16x8 bw1[10], bw2[8];
  {
    const int jr = jb + sl;
#pragma unroll
    for (int kt = 0; kt < 10; ++kt)
      bw1[kt] = *reinterpret_cast<const bf16x8*>(W1b + (size_t)jr * 160 + kt * 16 + hi * 8);
#pragma unroll
    for (int kt = 0; kt < 8; ++kt)
      bw2[kt] = *reinterpret_cast<const bf16x8*>(W2b + (size_t)jr * 128 + kt * 16 + hi * 8);
  }
  // biases packed bf16: C row j = jb + 8g + 4hi + r  (reg = 4g+r)
  u16x16 b1p, b2p;
#pragma unroll
  for (int g = 0; g < 4; ++g) {
#pragma unroll
    for (int r = 0; r < 4; ++r) {
      int j = jb + g * 8 + 4 * hi + r;
      b1p[g * 4 + r] = (unsigned short)(__builtin_bit_cast(unsigned int, b1[j]) >> 16);
      b2p[g * 4 + r] = (unsigned short)(__builtin_bit_cast(unsigned int, b2[j]) >> 16);
    }
  }

  // staging thread mapping
  const int xslot = tid >> 4, xq = tid & 15;   // x: slots xslot, xslot+32
  const int aslot = tid >> 3, aq = tid & 7;    // ea: one float4

  // prefetch registers
  bf16x8 pxv0 = {}, pxv1 = {};
  int peaidx = 0, pdst_ = 0;

  auto PREFETCH = [&](int t) {
    int p0 = t * TILE_E;
    int s0 = srcp[eperm[p0 + xslot]];
    int s1 = srcp[eperm[p0 + xslot + 32]];
    pxv0 = *reinterpret_cast<const bf16x8*>(xb + (size_t)s0 * ND + xq * 8);
    pxv1 = *reinterpret_cast<const bf16x8*>(xb + (size_t)s1 * ND + xq * 8);
    peaidx = eperm[p0 + aslot];
    if (tid < TILE_E) pdst_ = dsorted[p0 + tid];
  };

  int tile = blockIdx.x;
  if (tile < ntiles) PREFETCH(tile);

  for (; tile < ntiles; tile += gridDim.x) {
    __syncthreads();   // prev flush done before overwriting A/dstls

    // ---- staged regs -> LDS ----
    {
      *reinterpret_cast<bf16x8*>(AB + xslot * 320 + ((xq ^ (xslot & 15)) << 4)) = pxv0;
      int x2 = xslot + 32;
      *reinterpret_cast<bf16x8*>(AB + x2 * 320 + ((xq ^ (x2 & 15)) << 4)) = pxv1;
    }
    {
      float4 v = reinterpret_cast<const float4*>(ea)[(size_t)peaidx * 8 + aq];
      bf16x4 h;
      h[0] = (__bf16)v.x; h[1] = (__bf16)v.y; h[2] = (__bf16)v.z; h[3] = (__bf16)v.w;
      int pc = 16 + ((aq >> 1) ^ (aslot & 3));
      *reinterpret_cast<bf16x4*>(AB + aslot * 320 + (pc << 4) + ((aq & 1) << 3)) = h;
    }
    if (tid < TILE_E) dstls[tid] = pdst_;
    __syncthreads();

    // ---- prefetch next tile (hidden under MFMA) ----
    int nt = tile + gridDim.x;
    if (nt < ntiles) PREFETCH(nt);

    // ---- layer 1: H1^T[j][s] = silu(W1 . A^T + b1) ----
    {
      f32x16 acc;
#pragma unroll
      for (int i = 0; i < 16; ++i)
        acc[i] = __uint_as_float(((unsigned int)b1p[i]) << 16);
#pragma unroll
      for (int kt = 0; kt < 8; ++kt) {
        bf16x8 bf = *reinterpret_cast<const bf16x8*>(AB + s * 320 + (((2 * kt + hi) ^ sw) << 4));
        acc = mfma32(bw1[kt], bf, acc);
      }
#pragma unroll
      for (int kt = 0; kt < 2; ++kt) {
        bf16x8 bf = *reinterpret_cast<const bf16x8*>(AB + s * 320 + ((16 + ((2 * kt + hi) ^ (s & 3))) << 4));
        acc = mfma32(bw1[8 + kt], bf, acc);
      }
#pragma unroll
      for (int g = 0; g < 4; ++g) {
        bf16x4 h;
#pragma unroll
        for (int r = 0; r < 4; ++r) h[r] = (__bf16)fast_silu(acc[4 * g + r]);
        *reinterpret_cast<bf16x4*>(HB + s * 256 + ((((jb >> 3) + g) ^ sw) << 4) + 8 * hi) = h;
      }
    }
    __syncthreads();

    // ---- layer 2: M^T[j][s] = silu(W2 . H1^T + b2) -> M tile over A ----
    {
      f32x16 acc;
#pragma unroll
      for (int i = 0; i < 16; ++i)
        acc[i] = __uint_as_float(((unsigned int)b2p[i]) << 16);
#pragma unroll
      for (int kt = 0; kt < 8; ++kt) {
        bf16x8 bf = *reinterpret_cast<const bf16x8*>(HB + s * 256 + (((2 * kt + hi) ^ sw) << 4));
        acc = mfma32(bw2[kt], bf, acc);
      }
#pragma unroll
      for (int g = 0; g < 4; ++g) {
        bf16x4 m;
#pragma unroll
        for (int r = 0; r < 4; ++r) m[r] = (__bf16)fast_silu(acc[4 * g + r]);
        *reinterpret_cast<bf16x4*>(AB + s * 256 + ((((jb >> 3) + g) ^ sw) << 4) + 8 * hi) = m;
      }
    }
    __syncthreads();

    // ---- segmented flush: waves 0-3, 16 slots each, b32 col-pairs ----
    if (w < 4) {
      const int base = w * 16;
      int myd = dstls[base + (l & 15)];
      float a0 = 0.f, a1 = 0.f;
      int cur = __builtin_amdgcn_readlane(myd, 0);
#pragma unroll
      for (int i = 0; i < 16; ++i) {
        int nd = __builtin_amdgcn_readlane(myd, i);
        if (nd != cur) {
          atomicAdd(agg + (size_t)cur * HID + l * 2, a0);
          atomicAdd(agg + (size_t)cur * HID + l * 2 + 1, a1);
          a0 = 0.f; a1 = 0.f; cur = nd;
        }
        int ss = base + i;
        uint32_t u = *reinterpret_cast<const uint32_t*>(
            AB + ss * 256 + ((((l >> 2)) ^ (ss & 15)) << 4) + ((l & 3) << 2));
        a0 += __uint_as_float(u << 16);
        a1 += __uint_as_float(u & 0xffff0000u);
      }
      atomicAdd(agg + (size_t)cur * HID + l * 2, a0);
      atomicAdd(agg + (size_t)cur * HID + l * 2 + 1, a1);
    }
  }
}

// ================= GRU (weights-as-A, transposed, no LDS) =================
__global__ __launch_bounds__(512) void gru2(
    const float*  __restrict__ agg,      // [N,128] f32
    const __bf16* __restrict__ xb,
    const float*  __restrict__ x,
    const __bf16* __restrict__ Wih, const float* __restrict__ bih,  // [384,128]
    const __bf16* __restrict__ Whh, const float* __restrict__ bhh,
    float* __restrict__ out, int N)
{
  const int tid = threadIdx.x;
  const int w = tid >> 6, l = tid & 63;
  const int l4 = l >> 4, lm = l & 15;
  const int n0 = blockIdx.x * 64;
  const int jb = w * 16;
  const int jr = jb + lm, jz = jr + 128, jn = jr + 256;

  bf16x8 WiR[4], WhR[4], WiZ[4], WhZ[4], WiN[4], WhN[4];
#pragma unroll
  for (int kt = 0; kt < 4; ++kt) {
    int ko = kt * 32 + l4 * 8;
    WiR[kt] = *reinterpret_cast<const bf16x8*>(Wih + (size_t)jr * ND + ko);
    WhR[kt] = *reinterpret_cast<const bf16x8*>(Whh + (size_t)jr * ND + ko);
    WiZ[kt] = *reinterpret_cast<const bf16x8*>(Wih + (size_t)jz * ND + ko);
    WhZ[kt] = *reinterpret_cast<const bf16x8*>(Whh + (size_t)jz * ND + ko);
    WiN[kt] = *reinterpret_cast<const bf16x8*>(Wih + (size_t)jn * ND + ko);
    WhN[kt] = *reinterpret_cast<const bf16x8*>(Whh + (size_t)jn * ND + ko);
  }
  float4 birv, bizv, binv, bhnv;
  {
    int j0 = jb + l4 * 4;
    float4 a = *reinterpret_cast<const float4*>(bih + j0);
    float4 b = *reinterpret_cast<const float4*>(bhh + j0);
    birv = make_float4(a.x + b.x, a.y + b.y, a.z + b.z, a.w + b.w);
    a = *reinterpret_cast<const float4*>(bih + 128 + j0);
    b = *reinterpret_cast<const float4*>(bhh + 128 + j0);
    bizv = make_float4(a.x + b.x, a.y + b.y, a.z + b.z, a.w + b.w);
    binv = *reinterpret_cast<const float4*>(bih + 256 + j0);
    bhnv = *reinterpret_cast<const float4*>(bhh + 256 + j0);
  }

#pragma unroll
  for (int rt = 0; rt < 4; ++rt) {
    const int node = n0 + rt * 16 + lm;
    const bool ok = node < N;
    bf16x8 aA[4], aX[4];
#pragma unroll
    for (int kt = 0; kt < 4; ++kt) {
      int ko = kt * 32 + l4 * 8;
      bf16x8 z8 = {};
      if (ok) {
        float4 a0 = *reinterpret_cast<const float4*>(agg + (size_t)node * ND + ko);
        float4 a1 = *reinterpret_cast<const float4*>(agg + (size_t)node * ND + ko + 4);
        bf16x8 v;
        v[0] = (__bf16)a0.x; v[1] = (__bf16)a0.y; v[2] = (__bf16)a0.z; v[3] = (__bf16)a0.w;
        v[4] = (__bf16)a1.x; v[5] = (__bf16)a1.y; v[6] = (__bf16)a1.z; v[7] = (__bf16)a1.w;
        aA[kt] = v;
        aX[kt] = *reinterpret_cast<const bf16x8*>(xb + (size_t)node * ND + ko);
      } else {
        aA[kt] = z8;
        aX[kt] = z8;
      }
    }
    f32x4 aR = {0.f,0.f,0.f,0.f}, aZ = {0.f,0.f,0.f,0.f};
    f32x4 ai = {0.f,0.f,0.f,0.f}, ah = {0.f,0.f,0.f,0.f};
#pragma unroll
    for (int kt = 0; kt < 4; ++kt) {
      aR = mfma_bf16(WiR[kt], aA[kt], aR);
      aR = mfma_bf16(WhR[kt], aX[kt], aR);
      aZ = mfma_bf16(WiZ[kt], aA[kt], aZ);
      aZ = mfma_bf16(WhZ[kt], aX[kt], aZ);
      ai = mfma_bf16(WiN[kt], aA[kt], ai);
      ah = mfma_bf16(WhN[kt], aX[kt], ah);
    }
    if (ok) {
      float4 xv = *reinterpret_cast<const float4*>(x + (size_t)node * ND + jb + l4 * 4);
      float4 ov;
#pragma unroll
      for (int rr = 0; rr < 4; ++rr) {
        float r = fast_sigmoid(aR[rr] + (&birv.x)[rr]);
        float z = fast_sigmoid(aZ[rr] + (&bizv.x)[rr]);
        float n = fast_tanh(ai[rr] + (&binv.x)[rr] + r * (ah[rr] + (&bhnv.x)[rr]));
        (&ov.x)[rr] = (1.f - z) * n + z * (&xv.x)[rr];
      }
      *reinterpret_cast<float4*>(out + (size_t)node * ND + jb + l4 * 4) = ov;
    }
  }
}

extern "C" void kernel_launch(void* const* d_in, const int* in_sizes, int n_in,
                              void* d_out, int out_size, void* d_ws, size_t ws_size,
                              hipStream_t stream) {
  const float* x   = (const float*)d_in[0];
  const int*   ei  = (const int*)d_in[1];
  const float* ea  = (const float*)d_in[2];
  const float* W1  = (const float*)d_in[3];
  const float* b1  = (const float*)d_in[4];
  const float* W2  = (const float*)d_in[5];
  const float* b2  = (const float*)d_in[6];
  const float* Wih = (const float*)d_in[7];
  const float* bih = (const float*)d_in[8];
  const float* Whh = (const float*)d_in[9];
  const float* bhh = (const float*)d_in[10];
  float* out = (float*)d_out;
  const int N = in_sizes[0] / ND;       // 50000
  const int E = in_sizes[1] / 2;        // 800000

  const int nb = (N + 255) / 256;
  const int nC = nb * 256;

  char* ws = (char*)d_ws;
  size_t off = 0;
  auto alloc = [&](size_t bytes) -> void* {
    void* p = ws + off;
    off += (bytes + 255) & ~(size_t)255;
    return p;
  };
  __bf16* xb      = (__bf16*)alloc((size_t)N * ND * 2);
  __bf16* W1b     = (__bf16*)alloc(128 * 160 * 2);
  __bf16* W2b     = (__bf16*)alloc(128 * 128 * 2);
  __bf16* Wihb    = (__bf16*)alloc(384 * 128 * 2);
  __bf16* Whhb    = (__bf16*)alloc(384 * 128 * 2);
  int*    counts  = (int*)alloc((size_t)nC * 4);
  int*    cursor  = (int*)alloc((size_t)nC * 4);
  int*    bsum    = (int*)alloc(256 * 4);
  int*    eperm   = (int*)alloc((size_t)E * 4);
  int*    dsorted = (int*)alloc((size_t)E * 4);
  float*  agg     = (float*)alloc((size_t)N * ND * 4);
  (void)ws_size;

  const int* srcp = ei;
  const int* dstp = ei + E;

  hipMemsetAsync(agg, 0, (size_t)N * ND * 4, stream);
  hipMemsetAsync(counts, 0, (size_t)nC * 4, stream);

  const int n8_x = N * ND / 8, n8_1 = 128 * 160 / 8, n8_2 = 128 * 128 / 8, n8_g = 384 * 128 / 8;
  int c1 = n8_x, c2 = c1 + n8_1, c3 = c2 + n8_2, c4 = c3 + n8_g, c5 = c4 + n8_g;
  cvt_all<<<(c5 + 255) / 256, 256, 0, stream>>>(x, xb, c1, W1, W1b, c2, W2, W2b, c3,
                                                Wih, Wihb, c4, Whh, Whhb, c5);

  k_hist<<<(E + 255) / 256, 256, 0, stream>>>(dstp, counts, E);
  k_blocksum<<<nb, 256, 0, stream>>>(counts, bsum);
  k_scan_bsum<<<1, 256, 0, stream>>>(bsum, nb);
  k_scan_write<<<nb, 256, 0, stream>>>(counts, bsum, cursor);
  k_perm<<<(E + 255) / 256, 256, 0, stream>>>(dstp, cursor, eperm, dsorted, E);

  const int ntiles = E / TILE_E;   // 12500
  edge_mlp3<<<2500, 512, 0, stream>>>(xb, srcp, ea, W1b, b1, W2b, b2,
                                      eperm, dsorted, agg, ntiles);

  gru2<<<(N + 63) / 64, 512, 0, stream>>>(agg, xb, x, Wihb, bih, Whhb, bhh, out, N);
}

// Round 7
// 443.975 us; speedup vs baseline: 1.3848x; 1.3848x over previous
//
#include <hip/hip_runtime.h>
#include <hip/hip_bf16.h>
#include <cstdint>

typedef __bf16 bf16x8 __attribute__((ext_vector_type(8)));
typedef __bf16 bf16x4 __attribute__((ext_vector_type(4)));
typedef float  f32x4  __attribute__((ext_vector_type(4)));
typedef float  f32x16 __attribute__((ext_vector_type(16)));
typedef unsigned short u16x16 __attribute__((ext_vector_type(16)));

#define ND 128
#define HID 128

__device__ __forceinline__ f32x16 mfma32(bf16x8 a, bf16x8 b, f32x16 c) {
  return __builtin_amdgcn_mfma_f32_32x32x16_bf16(a, b, c, 0, 0, 0);
}
__device__ __forceinline__ float fast_sigmoid(float x) {
  return __fdividef(1.f, 1.f + __expf(-x));
}
__device__ __forceinline__ float fast_silu(float x) {
  return __fdividef(x, 1.f + __expf(-x));
}
__device__ __forceinline__ float fast_tanh(float x) {
  float cx = fminf(fmaxf(x, -15.f), 15.f);
  float e = __expf(2.f * cx);
  return __fdividef(e - 1.f, e + 1.f);
}
__device__ __forceinline__ f32x4 mfma_bf16(bf16x8 a, bf16x8 b, f32x4 c) {
  return __builtin_amdgcn_mfma_f32_16x16x32_bf16(a, b, c, 0, 0, 0);
}

// ---- fused f32 -> bf16 conversion over 5 segments ----
__global__ void cvt_all(const float* __restrict__ s0, __bf16* __restrict__ d0, int c1,
                        const float* __restrict__ s1, __bf16* __restrict__ d1, int c2,
                        const float* __restrict__ s2, __bf16* __restrict__ d2, int c3,
                        const float* __restrict__ s3, __bf16* __restrict__ d3, int c4,
                        const float* __restrict__ s4, __bf16* __restrict__ d4, int c5) {
  int i = blockIdx.x * blockDim.x + threadIdx.x;
  const float* s; __bf16* d; int j;
  if (i < c1)      { s = s0; d = d0; j = i; }
  else if (i < c2) { s = s1; d = d1; j = i - c1; }
  else if (i < c3) { s = s2; d = d2; j = i - c2; }
  else if (i < c4) { s = s3; d = d3; j = i - c3; }
  else if (i < c5) { s = s4; d = d4; j = i - c4; }
  else return;
  const float4* sp = reinterpret_cast<const float4*>(s) + (size_t)j * 2;
  float4 a = sp[0], b = sp[1];
  bf16x8 v;
  v[0] = (__bf16)a.x; v[1] = (__bf16)a.y; v[2] = (__bf16)a.z; v[3] = (__bf16)a.w;
  v[4] = (__bf16)b.x; v[5] = (__bf16)b.y; v[6] = (__bf16)b.z; v[7] = (__bf16)b.w;
  reinterpret_cast<bf16x8*>(d)[j] = v;
}

// ================= sort machinery =================
__global__ void k_hist(const int* __restrict__ dst, int* __restrict__ counts, int E) {
  int e = blockIdx.x * 256 + threadIdx.x;
  if (e < E) atomicAdd(&counts[dst[e]], 1);
}

__global__ void k_blocksum(const int* __restrict__ counts, int* __restrict__ bsum) {
  __shared__ int sd[256];
  int t = threadIdx.x;
  sd[t] = counts[blockIdx.x * 256 + t];
  __syncthreads();
  for (int d = 128; d > 0; d >>= 1) { if (t < d) sd[t] += sd[t + d]; __syncthreads(); }
  if (!t) bsum[blockIdx.x] = sd[0];
}

__global__ void k_scan_bsum(int* __restrict__ bsum, int nb) {
  __shared__ int sd[256];
  int t = threadIdx.x;
  int v = (t < nb) ? bsum[t] : 0;
  sd[t] = v;
  __syncthreads();
  for (int d = 1; d < 256; d <<= 1) {
    int u = (t >= d) ? sd[t - d] : 0;
    __syncthreads();
    sd[t] += u;
    __syncthreads();
  }
  if (t < nb) bsum[t] = sd[t] - v;
}

__global__ void k_scan_write(const int* __restrict__ counts, const int* __restrict__ bsum,
                             int* __restrict__ cursor) {
  __shared__ int sd[256];
  int t = threadIdx.x, b = blockIdx.x;
  int i = b * 256 + t;
  int c = counts[i];
  sd[t] = c;
  __syncthreads();
  for (int d = 1; d < 256; d <<= 1) {
    int u = (t >= d) ? sd[t - d] : 0;
    __syncthreads();
    sd[t] += u;
    __syncthreads();
  }
  cursor[i] = bsum[b] + sd[t] - c;   // exclusive prefix
}

__global__ void k_perm(const int* __restrict__ dst, int* __restrict__ cursor,
                       int* __restrict__ eperm, int* __restrict__ dsorted, int E) {
  int e = blockIdx.x * 256 + threadIdx.x;
  if (e < E) {
    int d = dst[e];
    int p = atomicAdd(&cursor[d], 1);
    eperm[p] = e;
    dsorted[p] = d;
  }
}

// ================= fused edge MLP + aggregate (32x32 MFMA) =================
// 8 waves = 4 j-strips(32) x 2 slot-halves(32). A tile [64][320B] chunks
// 0..15 = x (^ (s&15)), 16..19 = ea (^ (s&3)). H1 [64][256B] ^ (s&15).
// M (layer-2 out) overlays A as [64][256B] ^ (s&15). Flush: 8 waves x
// 8-slot groups, b32 column-pair lanes, readlane-uniform segmented scan.
// NOTE launch_bounds: empirically (512,4) capped VGPR at 64 and spilled the
// 18 weight fragments (r6: FETCH 797MB, 454us). (512,2) -> 128-VGPR cap.
#define TILE_E 64

__global__ __launch_bounds__(512, 2) void edge_mlp3(
    const __bf16* __restrict__ xb,
    const int*    __restrict__ srcp,     // [E]
    const float*  __restrict__ ea,       // [E,32]
    const __bf16* __restrict__ W1b,      // [128,160]
    const float*  __restrict__ b1,
    const __bf16* __restrict__ W2b,      // [128,128]
    const float*  __restrict__ b2,
    const int*    __restrict__ eperm,    // [E] slot -> edge
    const int*    __restrict__ dsorted,  // [E] slot -> dst node
    float* __restrict__ agg,             // [N,128] f32, zeroed
    int ntiles)
{
  __shared__ __bf16 Als[TILE_E * 160];   // 20480 B; first 16 KB reused as M
  __shared__ __bf16 H1[TILE_E * 128];    // 16384 B
  __shared__ int dstls[TILE_E];
  char* AB = (char*)Als;
  char* HB = (char*)H1;

  const int tid = threadIdx.x;
  const int w   = tid >> 6;
  const int l   = tid & 63;
  const int hi  = l >> 5;            // k-half within fragment
  const int sl  = l & 31;
  const int jb  = (w & 3) * 32;      // j-strip base
  const int sh  = (w >> 2) * 32;     // slot-half base
  const int s   = sh + sl;           // this lane's B-operand slot
  const int sw  = s & 15;

  // weight A-fragments: row j = jb + sl, k = kt*16 + hi*8 (16B contiguous)
  bf16x8 bw1[10], bw2[8];
  {
    const int jr = jb + sl;
#pragma unroll
    for (int kt = 0; kt < 10; ++kt)
      bw1[kt] = *reinterpret_cast<const bf16x8*>(W1b + (size_t)jr * 160 + kt * 16 + hi * 8);
#pragma unroll
    for (int kt = 0; kt < 8; ++kt)
      bw2[kt] = *reinterpret_cast<const bf16x8*>(W2b + (size_t)jr * 128 + kt * 16 + hi * 8);
  }
  // biases packed bf16: C row j = jb + 8g + 4hi + r  (reg = 4g+r)
  u16x16 b1p, b2p;
#pragma unroll
  for (int g = 0; g < 4; ++g) {
#pragma unroll
    for (int r = 0; r < 4; ++r) {
      int j = jb + g * 8 + 4 * hi + r;
      b1p[g * 4 + r] = (unsigned short)(__builtin_bit_cast(unsigned int, b1[j]) >> 16);
      b2p[g * 4 + r] = (unsigned short)(__builtin_bit_cast(unsigned int, b2[j]) >> 16);
    }
  }

  // staging thread mapping
  const int xslot = tid >> 4, xq = tid & 15;   // x: slots xslot, xslot+32
  const int aslot = tid >> 3, aq = tid & 7;    // ea: one float4

  // prefetch registers
  bf16x8 pxv0 = {}, pxv1 = {};
  int peaidx = 0, pdst_ = 0;

  auto PREFETCH = [&](int t) {
    int p0 = t * TILE_E;
    int s0 = srcp[eperm[p0 + xslot]];
    int s1 = srcp[eperm[p0 + xslot + 32]];
    pxv0 = *reinterpret_cast<const bf16x8*>(xb + (size_t)s0 * ND + xq * 8);
    pxv1 = *reinterpret_cast<const bf16x8*>(xb + (size_t)s1 * ND + xq * 8);
    peaidx = eperm[p0 + aslot];
    if (tid < TILE_E) pdst_ = dsorted[p0 + tid];
  };

  int tile = blockIdx.x;
  if (tile < ntiles) PREFETCH(tile);

  for (; tile < ntiles; tile += gridDim.x) {
    __syncthreads();   // prev flush done before overwriting A/dstls

    // ---- staged regs -> LDS ----
    {
      *reinterpret_cast<bf16x8*>(AB + xslot * 320 + ((xq ^ (xslot & 15)) << 4)) = pxv0;
      int x2 = xslot + 32;
      *reinterpret_cast<bf16x8*>(AB + x2 * 320 + ((xq ^ (x2 & 15)) << 4)) = pxv1;
    }
    {
      float4 v = reinterpret_cast<const float4*>(ea)[(size_t)peaidx * 8 + aq];
      bf16x4 h;
      h[0] = (__bf16)v.x; h[1] = (__bf16)v.y; h[2] = (__bf16)v.z; h[3] = (__bf16)v.w;
      int pc = 16 + ((aq >> 1) ^ (aslot & 3));
      *reinterpret_cast<bf16x4*>(AB + aslot * 320 + (pc << 4) + ((aq & 1) << 3)) = h;
    }
    if (tid < TILE_E) dstls[tid] = pdst_;
    __syncthreads();

    // ---- prefetch next tile (hidden under MFMA) ----
    int nt = tile + gridDim.x;
    if (nt < ntiles) PREFETCH(nt);

    // ---- layer 1: H1^T[j][s] = silu(W1 . A^T + b1) ----
    {
      f32x16 acc;
#pragma unroll
      for (int i = 0; i < 16; ++i)
        acc[i] = __uint_as_float(((unsigned int)b1p[i]) << 16);
#pragma unroll
      for (int kt = 0; kt < 8; ++kt) {
        bf16x8 bf = *reinterpret_cast<const bf16x8*>(AB + s * 320 + (((2 * kt + hi) ^ sw) << 4));
        acc = mfma32(bw1[kt], bf, acc);
      }
#pragma unroll
      for (int kt = 0; kt < 2; ++kt) {
        bf16x8 bf = *reinterpret_cast<const bf16x8*>(AB + s * 320 + ((16 + ((2 * kt + hi) ^ (s & 3))) << 4));
        acc = mfma32(bw1[8 + kt], bf, acc);
      }
#pragma unroll
      for (int g = 0; g < 4; ++g) {
        bf16x4 h;
#pragma unroll
        for (int r = 0; r < 4; ++r) h[r] = (__bf16)fast_silu(acc[4 * g + r]);
        *reinterpret_cast<bf16x4*>(HB + s * 256 + ((((jb >> 3) + g) ^ sw) << 4) + 8 * hi) = h;
      }
    }
    __syncthreads();

    // ---- layer 2: M^T[j][s] = silu(W2 . H1^T + b2) -> M tile over A ----
    {
      f32x16 acc;
#pragma unroll
      for (int i = 0; i < 16; ++i)
        acc[i] = __uint_as_float(((unsigned int)b2p[i]) << 16);
#pragma unroll
      for (int kt = 0; kt < 8; ++kt) {
        bf16x8 bf = *reinterpret_cast<const bf16x8*>(HB + s * 256 + (((2 * kt + hi) ^ sw) << 4));
        acc = mfma32(bw2[kt], bf, acc);
      }
#pragma unroll
      for (int g = 0; g < 4; ++g) {
        bf16x4 m;
#pragma unroll
        for (int r = 0; r < 4; ++r) m[r] = (__bf16)fast_silu(acc[4 * g + r]);
        *reinterpret_cast<bf16x4*>(AB + s * 256 + ((((jb >> 3) + g) ^ sw) << 4) + 8 * hi) = m;
      }
    }
    __syncthreads();

    // ---- segmented flush: 8 waves x 8-slot groups, b32 col-pairs ----
    {
      const int base = w * 8;
      int myd = dstls[base + (l & 7)];
      float a0 = 0.f, a1 = 0.f;
      int cur = __builtin_amdgcn_readlane(myd, 0);
#pragma unroll
      for (int i = 0; i < 8; ++i) {
        int nd = __builtin_amdgcn_readlane(myd, i);
        if (nd != cur) {
          atomicAdd(agg + (size_t)cur * HID + l * 2, a0);
          atomicAdd(agg + (size_t)cur * HID + l * 2 + 1, a1);
          a0 = 0.f; a1 = 0.f; cur = nd;
        }
        int ss = base + i;
        uint32_t u = *reinterpret_cast<const uint32_t*>(
            AB + ss * 256 + (((l >> 2) ^ (ss & 15)) << 4) + ((l & 3) << 2));
        a0 += __uint_as_float(u << 16);
        a1 += __uint_as_float(u & 0xffff0000u);
      }
      atomicAdd(agg + (size_t)cur * HID + l * 2, a0);
      atomicAdd(agg + (size_t)cur * HID + l * 2 + 1, a1);
    }
  }
}

// ================= GRU (weights-as-A, transposed, no LDS) =================
__global__ __launch_bounds__(512) void gru2(
    const float*  __restrict__ agg,      // [N,128] f32
    const __bf16* __restrict__ xb,
    const float*  __restrict__ x,
    const __bf16* __restrict__ Wih, const float* __restrict__ bih,  // [384,128]
    const __bf16* __restrict__ Whh, const float* __restrict__ bhh,
    float* __restrict__ out, int N)
{
  const int tid = threadIdx.x;
  const int w = tid >> 6, l = tid & 63;
  const int l4 = l >> 4, lm = l & 15;
  const int n0 = blockIdx.x * 64;
  const int jb = w * 16;
  const int jr = jb + lm, jz = jr + 128, jn = jr + 256;

  bf16x8 WiR[4], WhR[4], WiZ[4], WhZ[4], WiN[4], WhN[4];
#pragma unroll
  for (int kt = 0; kt < 4; ++kt) {
    int ko = kt * 32 + l4 * 8;
    WiR[kt] = *reinterpret_cast<const bf16x8*>(Wih + (size_t)jr * ND + ko);
    WhR[kt] = *reinterpret_cast<const bf16x8*>(Whh + (size_t)jr * ND + ko);
    WiZ[kt] = *reinterpret_cast<const bf16x8*>(Wih + (size_t)jz * ND + ko);
    WhZ[kt] = *reinterpret_cast<const bf16x8*>(Whh + (size_t)jz * ND + ko);
    WiN[kt] = *reinterpret_cast<const bf16x8*>(Wih + (size_t)jn * ND + ko);
    WhN[kt] = *reinterpret_cast<const bf16x8*>(Whh + (size_t)jn * ND + ko);
  }
  float4 birv, bizv, binv, bhnv;
  {
    int j0 = jb + l4 * 4;
    float4 a = *reinterpret_cast<const float4*>(bih + j0);
    float4 b = *reinterpret_cast<const float4*>(bhh + j0);
    birv = make_float4(a.x + b.x, a.y + b.y, a.z + b.z, a.w + b.w);
    a = *reinterpret_cast<const float4*>(bih + 128 + j0);
    b = *reinterpret_cast<const float4*>(bhh + 128 + j0);
    bizv = make_float4(a.x + b.x, a.y + b.y, a.z + b.z, a.w + b.w);
    binv = *reinterpret_cast<const float4*>(bih + 256 + j0);
    bhnv = *reinterpret_cast<const float4*>(bhh + 256 + j0);
  }

#pragma unroll
  for (int rt = 0; rt < 4; ++rt) {
    const int node = n0 + rt * 16 + lm;
    const bool ok = node < N;
    bf16x8 aA[4], aX[4];
#pragma unroll
    for (int kt = 0; kt < 4; ++kt) {
      int ko = kt * 32 + l4 * 8;
      bf16x8 z8 = {};
      if (ok) {
        float4 a0 = *reinterpret_cast<const float4*>(agg + (size_t)node * ND + ko);
        float4 a1 = *reinterpret_cast<const float4*>(agg + (size_t)node * ND + ko + 4);
        bf16x8 v;
        v[0] = (__bf16)a0.x; v[1] = (__bf16)a0.y; v[2] = (__bf16)a0.z; v[3] = (__bf16)a0.w;
        v[4] = (__bf16)a1.x; v[5] = (__bf16)a1.y; v[6] = (__bf16)a1.z; v[7] = (__bf16)a1.w;
        aA[kt] = v;
        aX[kt] = *reinterpret_cast<const bf16x8*>(xb + (size_t)node * ND + ko);
      } else {
        aA[kt] = z8;
        aX[kt] = z8;
      }
    }
    f32x4 aR = {0.f,0.f,0.f,0.f}, aZ = {0.f,0.f,0.f,0.f};
    f32x4 ai = {0.f,0.f,0.f,0.f}, ah = {0.f,0.f,0.f,0.f};
#pragma unroll
    for (int kt = 0; kt < 4; ++kt) {
      aR = mfma_bf16(WiR[kt], aA[kt], aR);
      aR = mfma_bf16(WhR[kt], aX[kt], aR);
      aZ = mfma_bf16(WiZ[kt], aA[kt], aZ);
      aZ = mfma_bf16(WhZ[kt], aX[kt], aZ);
      ai = mfma_bf16(WiN[kt], aA[kt], ai);
      ah = mfma_bf16(WhN[kt], aX[kt], ah);
    }
    if (ok) {
      float4 xv = *reinterpret_cast<const float4*>(x + (size_t)node * ND + jb + l4 * 4);
      float4 ov;
#pragma unroll
      for (int rr = 0; rr < 4; ++rr) {
        float r = fast_sigmoid(aR[rr] + (&birv.x)[rr]);
        float z = fast_sigmoid(aZ[rr] + (&bizv.x)[rr]);
        float n = fast_tanh(ai[rr] + (&binv.x)[rr] + r * (ah[rr] + (&bhnv.x)[rr]));
        (&ov.x)[rr] = (1.f - z) * n + z * (&xv.x)[rr];
      }
      *reinterpret_cast<float4*>(out + (size_t)node * ND + jb + l4 * 4) = ov;
    }
  }
}

extern "C" void kernel_launch(void* const* d_in, const int* in_sizes, int n_in,
                              void* d_out, int out_size, void* d_ws, size_t ws_size,
                              hipStream_t stream) {
  const float* x   = (const float*)d_in[0];
  const int*   ei  = (const int*)d_in[1];
  const float* ea  = (const float*)d_in[2];
  const float* W1  = (const float*)d_in[3];
  const float* b1  = (const float*)d_in[4];
  const float* W2  = (const float*)d_in[5];
  const float* b2  = (const float*)d_in[6];
  const float* Wih = (const float*)d_in[7];
  const float* bih = (const float*)d_in[8];
  const float* Whh = (const float*)d_in[9];
  const float* bhh = (const float*)d_in[10];
  float* out = (float*)d_out;
  const int N = in_sizes[0] / ND;       // 50000
  const int E = in_sizes[1] / 2;        // 800000

  const int nb = (N + 255) / 256;
  const int nC = nb * 256;

  char* ws = (char*)d_ws;
  size_t off = 0;
  auto alloc = [&](size_t bytes) -> void* {
    void* p = ws + off;
    off += (bytes + 255) & ~(size_t)255;
    return p;
  };
  __bf16* xb      = (__bf16*)alloc((size_t)N * ND * 2);
  __bf16* W1b     = (__bf16*)alloc(128 * 160 * 2);
  __bf16* W2b     = (__bf16*)alloc(128 * 128 * 2);
  __bf16* Wihb    = (__bf16*)alloc(384 * 128 * 2);
  __bf16* Whhb    = (__bf16*)alloc(384 * 128 * 2);
  int*    counts  = (int*)alloc((size_t)nC * 4);
  int*    cursor  = (int*)alloc((size_t)nC * 4);
  int*    bsum    = (int*)alloc(256 * 4);
  int*    eperm   = (int*)alloc((size_t)E * 4);
  int*    dsorted = (int*)alloc((size_t)E * 4);
  float*  agg     = (float*)alloc((size_t)N * ND * 4);
  (void)ws_size;

  const int* srcp = ei;
  const int* dstp = ei + E;

  hipMemsetAsync(agg, 0, (size_t)N * ND * 4, stream);
  hipMemsetAsync(counts, 0, (size_t)nC * 4, stream);

  const int n8_x = N * ND / 8, n8_1 = 128 * 160 / 8, n8_2 = 128 * 128 / 8, n8_g = 384 * 128 / 8;
  int c1 = n8_x, c2 = c1 + n8_1, c3 = c2 + n8_2, c4 = c3 + n8_g, c5 = c4 + n8_g;
  cvt_all<<<(c5 + 255) / 256, 256, 0, stream>>>(x, xb, c1, W1, W1b, c2, W2, W2b, c3,
                                                Wih, Wihb, c4, Whh, Whhb, c5);

  k_hist<<<(E + 255) / 256, 256, 0, stream>>>(dstp, counts, E);
  k_blocksum<<<nb, 256, 0, stream>>>(counts, bsum);
  k_scan_bsum<<<1, 256, 0, stream>>>(bsum, nb);
  k_scan_write<<<nb, 256, 0, stream>>>(counts, bsum, cursor);
  k_perm<<<(E + 255) / 256, 256, 0, stream>>>(dstp, cursor, eperm, dsorted, E);

  const int ntiles = E / TILE_E;   // 12500
  edge_mlp3<<<2500, 512, 0, stream>>>(xb, srcp, ea, W1b, b1, W2b, b2,
                                      eperm, dsorted, agg, ntiles);

  gru2<<<(N + 63) / 64, 512, 0, stream>>>(agg, xb, x, Wihb, bih, Whhb, bhh, out, N);
}